// Round 1
// baseline (2661.450 us; speedup 1.0000x reference)
//
#include <hip/hip_runtime.h>
#include <math.h>

#define PI_D 3.14159265358979323846

// sizes
#define BSZ   512
#define NODE  66
#define HID   512
#define VL    35
#define VN    16
#define DCTN  20
#define GCNIN 40

static constexpr float BN_INVS = 0.99999500003749969f; // 1/sqrt(1+1e-5)

// ---------------- dct20 (20 x 35), orthonormal DCT-II rows ----------------
__global__ void dct_kernel(float* __restrict__ dct20) {
    int i = blockIdx.x * blockDim.x + threadIdx.x;
    if (i < DCTN * VL) {
        int k = i / VL, v = i - k * VL;
        double w = (k == 0) ? sqrt(1.0 / VL) : sqrt(2.0 / VL);
        dct20[i] = (float)(w * cos(PI_D * (v + 0.5) * k / (double)VL));
    }
}

// ---------------- conv1: (bs,66,TIN) -> relu -> (bs,512,TOUT) ----------------
// in comes from src (bs,50,66) transposed+scaled on the fly
template<int TIN, int T0, int TOUT>
__global__ __launch_bounds__(256) void conv1_relu(const float* __restrict__ src,
                                                  const float* __restrict__ W,
                                                  float* __restrict__ out) {
    const int b = blockIdx.x, tid = threadIdx.x;
    __shared__ float s_in[TIN * 66];
    for (int i = tid; i < TIN * 66; i += 256) {
        int t = i / 66, c = i - t * 66;
        s_in[i] = src[b * 3300 + (T0 + t) * 66 + c] * 1e-3f;
    }
    __syncthreads();
    for (int o = tid; o < 512 * TOUT; o += 256) {
        int d = o / TOUT, t = o - (o / TOUT) * TOUT;
        const float* w = W + d * 396;
        float acc = 0.f;
        for (int c = 0; c < 66; ++c) {
#pragma unroll
            for (int h = 0; h < 6; ++h)
                acc += w[c * 6 + h] * s_in[(t + h) * 66 + c];
        }
        out[b * 512 * TOUT + o] = fmaxf(acc, 0.f);
    }
}

// ---------------- conv2 as implicit GEMM ----------------
// out[b,d,t] = relu( sum_{c,h} W2[d,c,h] * in[b,c,t+h] )
// M rows R=(b*TOUT+t), N=512 (d), K=2560 (c*5+h). Output layout (b, t, d) = outT[R*512+d].
template<int TIN, int TOUT>
__global__ __launch_bounds__(256) void conv2_gemm(const float* __restrict__ in,
                                                  const float* __restrict__ W2,
                                                  float* __restrict__ outT) {
    __shared__ float As[16][68];
    __shared__ float Bs[16][68];
    const int tid = threadIdx.x;
    const int r0 = blockIdx.x * 64, n0 = blockIdx.y * 64;
    const int ty = tid >> 4, tx = tid & 15;
    // A loader: 4 scattered scalar loads per thread
    const int arow = tid >> 2, akq = tid & 3;
    const int R = r0 + arow;
    const int ab = R / TOUT, at = R - ab * TOUT;
    const float* ain = in + ab * 512 * TIN + at;
    // B loader: float4 along k for one d
    const int bcol = tid >> 2, bkq = tid & 3;
    const float* bw = W2 + (size_t)(n0 + bcol) * 2560 + bkq * 4;
    float acc[4][4] = {};
    for (int k0 = 0; k0 < 2560; k0 += 16) {
#pragma unroll
        for (int j = 0; j < 4; ++j) {
            int k = k0 + akq * 4 + j;
            int c = k / 5, h = k - c * 5;
            As[akq * 4 + j][arow] = ain[c * TIN + h];
        }
        float4 bv = *(const float4*)(bw + k0);
        Bs[bkq * 4 + 0][bcol] = bv.x;
        Bs[bkq * 4 + 1][bcol] = bv.y;
        Bs[bkq * 4 + 2][bcol] = bv.z;
        Bs[bkq * 4 + 3][bcol] = bv.w;
        __syncthreads();
#pragma unroll
        for (int kk = 0; kk < 16; ++kk) {
            float4 a = *(const float4*)&As[kk][ty * 4];
            float4 bb = *(const float4*)&Bs[kk][tx * 4];
            float ar[4] = {a.x, a.y, a.z, a.w};
            float br[4] = {bb.x, bb.y, bb.z, bb.w};
#pragma unroll
            for (int i = 0; i < 4; ++i)
#pragma unroll
                for (int j = 0; j < 4; ++j) acc[i][j] += ar[i] * br[j];
        }
        __syncthreads();
    }
#pragma unroll
    for (int i = 0; i < 4; ++i) {
        float4 v = make_float4(fmaxf(acc[i][0], 0.f), fmaxf(acc[i][1], 0.f),
                               fmaxf(acc[i][2], 0.f), fmaxf(acc[i][3], 0.f));
        *(float4*)&outT[(size_t)(r0 + ty * 4 + i) * 512 + n0 + tx * 4] = v;
    }
}

// ---------------- attention weights: att[b,n] ----------------
// qT: (bs,512), kT: (bs,16,512)
__global__ __launch_bounds__(256) void att_kernel(const float* __restrict__ qT,
                                                  const float* __restrict__ kT,
                                                  float* __restrict__ att) {
    const int b = blockIdx.x, tid = threadIdx.x;
    __shared__ float part[256];
    __shared__ float sc[16];
    int n = tid >> 4, j = tid & 15;
    const float* q = qT + b * 512;
    const float* k = kT + b * 8192 + n * 512;
    float acc = 0.f;
    for (int d = j; d < 512; d += 16) acc += q[d] * k[d];
    part[tid] = acc;
    __syncthreads();
    if (tid < 16) {
        float s = 0.f;
        for (int jj = 0; jj < 16; ++jj) s += part[tid * 16 + jj];
        sc[tid] = s + 1e-15f;
    }
    __syncthreads();
    if (tid == 0) {
        float tot = 0.f;
        for (int nn = 0; nn < 16; ++nn) tot += sc[nn];
        float inv = 1.f / tot;
        for (int nn = 0; nn < 16; ++nn) att[b * 16 + nn] = sc[nn] * inv;
    }
}

// ---------------- build x = concat(dct_in, dct_att) : (bs,66,40) ----------------
__global__ __launch_bounds__(256) void xbuild(const float* __restrict__ src,
                                              const float* __restrict__ att,
                                              const float* __restrict__ dct20,
                                              float* __restrict__ x) {
    const int b = blockIdx.x, tid = threadIdx.x;
    __shared__ float s_src[50 * 66];
    __shared__ float s_sacc[VL * 66];
    __shared__ float s_d[DCTN * VL];
    __shared__ float s_att[16];
    for (int i = tid; i < 3300; i += 256) s_src[i] = src[b * 3300 + i];
    for (int i = tid; i < DCTN * VL; i += 256) s_d[i] = dct20[i];
    if (tid < 16) s_att[tid] = att[b * 16 + tid];
    __syncthreads();
    for (int i = tid; i < VL * 66; i += 256) {
        int v = i / 66, f = i - v * 66;
        float a = 0.f;
#pragma unroll
        for (int n = 0; n < 16; ++n) a += s_att[n] * s_src[(n + v) * 66 + f];
        s_sacc[i] = a;
    }
    __syncthreads();
    for (int i = tid; i < 66 * DCTN; i += 256) {
        int f = i / DCTN, kq = i - (i / DCTN) * DCTN;
        float din = 0.f, datt = 0.f;
        for (int v = 0; v < VL; ++v) {
            float dv = s_d[kq * VL + v];
            int t2 = (v < 10) ? (40 + v) : 49;
            din += dv * s_src[t2 * 66 + f];
            datt += dv * s_sacc[v * 66 + f];
        }
        x[b * 2640 + f * 40 + kq] = din;
        x[b * 2640 + f * 40 + 20 + kq] = datt;
    }
}

// ---------------- small GEMM: t[r,c] = sum_{k<40} x[r,k]*W[k,c] ----------------
__global__ __launch_bounds__(256) void gemm_k40(const float* __restrict__ x,
                                                const float* __restrict__ W,
                                                float* __restrict__ t) {
    const int r0 = blockIdx.x * 4, tid = threadIdx.x;
    __shared__ float xs[4][40];
    for (int i = tid; i < 160; i += 256) xs[i / 40][i - (i / 40) * 40] = x[r0 * 40 + i];
    __syncthreads();
    for (int o = tid; o < 2048; o += 256) {
        int rr = o >> 9, c = o & 511;
        float acc = 0.f;
#pragma unroll
        for (int k = 0; k < 40; ++k) acc += xs[rr][k] * W[k * 512 + c];
        t[(size_t)(r0 + rr) * 512 + c] = acc;
    }
}

// ---------------- tiled fp32 GEMM: C[M,N] = A[M,K] @ B[K,N] (row-major) ------
__global__ __launch_bounds__(256) void gemm_tiled(const float* __restrict__ A,
                                                  const float* __restrict__ B,
                                                  float* __restrict__ C,
                                                  int K, int N) {
    __shared__ float As[16][68];
    __shared__ float Bs[16][68];
    const int tid = threadIdx.x;
    const int r0 = blockIdx.x * 64, n0 = blockIdx.y * 64;
    const int ty = tid >> 4, tx = tid & 15;
    const int arow = tid >> 2, akq = tid & 3;
    const int bkk = tid >> 4, bcq = tid & 15;
    const float* ap = A + (size_t)(r0 + arow) * K + akq * 4;
    const float* bp = B + (size_t)bkk * N + n0 + bcq * 4;
    float acc[4][4] = {};
    for (int k0 = 0; k0 < K; k0 += 16) {
        float4 av = *(const float4*)(ap + k0);
        As[akq * 4 + 0][arow] = av.x;
        As[akq * 4 + 1][arow] = av.y;
        As[akq * 4 + 2][arow] = av.z;
        As[akq * 4 + 3][arow] = av.w;
        float4 bv = *(const float4*)(bp + (size_t)k0 * N);
        *(float4*)&Bs[bkk][bcq * 4] = bv;
        __syncthreads();
#pragma unroll
        for (int kk = 0; kk < 16; ++kk) {
            float4 a = *(const float4*)&As[kk][ty * 4];
            float4 bb = *(const float4*)&Bs[kk][tx * 4];
            float ar[4] = {a.x, a.y, a.z, a.w};
            float br[4] = {bb.x, bb.y, bb.z, bb.w};
#pragma unroll
            for (int i = 0; i < 4; ++i)
#pragma unroll
                for (int j = 0; j < 4; ++j) acc[i][j] += ar[i] * br[j];
        }
        __syncthreads();
    }
#pragma unroll
    for (int i = 0; i < 4; ++i) {
        float4 v = make_float4(acc[i][0], acc[i][1], acc[i][2], acc[i][3]);
        *(float4*)&C[(size_t)(r0 + ty * 4 + i) * N + n0 + tx * 4] = v;
    }
}

// ---------------- A-mult + bias + bn + tanh (+residual) ----------------
// z[b,n,f] = sum_m A[n,m]*t[b,m,f] + bias[f]; y = tanh(z*g'[n,f]+be[n,f]) (+ yres)
__global__ __launch_bounds__(256) void amult_bn_tanh(const float* __restrict__ t,
                                                     const float* __restrict__ A,
                                                     const float* __restrict__ bias,
                                                     const float* __restrict__ g,
                                                     const float* __restrict__ be,
                                                     const float* __restrict__ yres,
                                                     float* __restrict__ yout) {
    const int b = blockIdx.x >> 2;
    const int f0 = (blockIdx.x & 3) * 128;
    const int tid = threadIdx.x;
    __shared__ float ts[66][128];
    __shared__ float As[4752]; // 66*66 used; tail garbage (guarded writes)
    for (int i = tid; i < 66 * 128; i += 256) {
        int m = i >> 7, f = i & 127;
        ts[m][f] = t[(size_t)b * 33792 + m * 512 + f0 + f];
    }
    for (int i = tid; i < 4356; i += 256) As[i] = A[i];
    __syncthreads();
    for (int task = tid; task < 288; task += 256) {
        int q = task & 31;    // feature quad: f = f0 + q*4 + j
        int n0 = (task >> 5) * 8;
        float acc[8][4] = {};
        for (int m = 0; m < 66; ++m) {
            float4 tv = *(const float4*)&ts[m][q * 4];
#pragma unroll
            for (int i = 0; i < 8; ++i) {
                float a = As[(n0 + i) * 66 + m];
                acc[i][0] += a * tv.x;
                acc[i][1] += a * tv.y;
                acc[i][2] += a * tv.z;
                acc[i][3] += a * tv.w;
            }
        }
#pragma unroll
        for (int i = 0; i < 8; ++i) {
            int n = n0 + i;
            if (n < 66) {
#pragma unroll
                for (int j = 0; j < 4; ++j) {
                    int f = f0 + q * 4 + j;
                    int gi = n * 512 + f;
                    float z = acc[i][j] + bias[f];
                    float v = tanhf(z * (g[gi] * BN_INVS) + be[gi]);
                    if (yres) v += yres[(size_t)b * 33792 + gi];
                    yout[(size_t)b * 33792 + gi] = v;
                }
            }
        }
    }
}

// ---------------- t2[r,c<20] = sum_k y[r,k]*W7[k,c] ----------------
__global__ __launch_bounds__(256) void gemm_n20(const float* __restrict__ y,
                                                const float* __restrict__ W7,
                                                float* __restrict__ t2) {
    const int r0 = blockIdx.x * 8, tid = threadIdx.x;
    __shared__ float ys[8][512];
    for (int i = tid; i < 4096; i += 256) ys[i >> 9][i & 511] = y[(size_t)r0 * 512 + i];
    __syncthreads();
    for (int o = tid; o < 160; o += 256) {
        int rr = o / 20, c = o - (o / 20) * 20;
        float acc = 0.f;
        for (int k = 0; k < 512; ++k) acc += ys[rr][k] * W7[k * 40 + c];
        t2[(size_t)(r0 + rr) * 20 + c] = acc;
    }
}

// ---------------- dctout[b,n,c] = sum_m A7[n,m]*t2[b,m,c] + b7[c] + x[b,n,c] --
__global__ __launch_bounds__(256) void gc7_amult(const float* __restrict__ t2,
                                                 const float* __restrict__ A7,
                                                 const float* __restrict__ b7,
                                                 const float* __restrict__ x,
                                                 float* __restrict__ dctout) {
    const int b = blockIdx.x, tid = threadIdx.x;
    __shared__ float ts[66 * 20];
    __shared__ float As[66 * 66];
    for (int i = tid; i < 1320; i += 256) ts[i] = t2[(size_t)b * 1320 + i];
    for (int i = tid; i < 4356; i += 256) As[i] = A7[i];
    __syncthreads();
    for (int o = tid; o < 1320; o += 256) {
        int n = o / 20, c = o - (o / 20) * 20;
        float acc = b7[c] + x[(size_t)b * 2640 + n * 40 + c];
        for (int m = 0; m < 66; ++m) acc += As[n * 66 + m] * ts[m * 20 + c];
        dctout[(size_t)b * 1320 + o] = acc;
    }
}

// ---------------- out[b,v,f] = sum_k dct20[k,v]*dctout[b,f,k] ----------------
__global__ __launch_bounds__(256) void final_out(const float* __restrict__ dctout,
                                                 const float* __restrict__ dct20,
                                                 float* __restrict__ out) {
    const int b = blockIdx.x, tid = threadIdx.x;
    __shared__ float ds[DCTN * VL];
    __shared__ float dos[66 * 20];
    for (int i = tid; i < DCTN * VL; i += 256) ds[i] = dct20[i];
    for (int i = tid; i < 1320; i += 256) dos[i] = dctout[(size_t)b * 1320 + i];
    __syncthreads();
    for (int o = tid; o < VL * 66; o += 256) {
        int v = o / 66, f = o - (o / 66) * 66;
        float acc = 0.f;
#pragma unroll
        for (int k = 0; k < DCTN; ++k) acc += ds[k * VL + v] * dos[f * 20 + k];
        out[(size_t)b * 2310 + o] = acc;
    }
}

extern "C" void kernel_launch(void* const* d_in, const int* in_sizes, int n_in,
                              void* d_out, int out_size, void* d_ws, size_t ws_size,
                              hipStream_t stream) {
    const float* src     = (const float*)d_in[0];
    const float* Wq1     = (const float*)d_in[1];
    const float* Wq2     = (const float*)d_in[2];
    const float* Wk1     = (const float*)d_in[3];
    const float* Wk2     = (const float*)d_in[4];
    const float* gc1_W   = (const float*)d_in[5];
    const float* gc1_att = (const float*)d_in[6];
    const float* gc1_b   = (const float*)d_in[7];
    const float* bn1_g   = (const float*)d_in[8];
    const float* bn1_b   = (const float*)d_in[9];
    const float* gcb_W   = (const float*)d_in[10];
    const float* gcb_att = (const float*)d_in[11];
    const float* gcb_b   = (const float*)d_in[12];
    const float* gcb_g   = (const float*)d_in[13];
    const float* gcb_be  = (const float*)d_in[14];
    const float* gc7_W   = (const float*)d_in[15];
    const float* gc7_att = (const float*)d_in[16];
    const float* gc7_b   = (const float*)d_in[17];
    float* out = (float*)d_out;

    float* ws = (float*)d_ws;
    const size_t SYf = (size_t)BSZ * NODE * HID; // 17,301,504 floats
    float* yA     = ws;
    float* yB     = ws + SYf;
    float* tb     = ws + 2 * SYf;
    float* xb     = ws + 3 * SYf;          // 1,351,680
    float* dct20  = xb + 1351680;          // 700 (pad to 1024)
    float* dctout = dct20 + 1024;          // 675,840
    // early-phase aliases inside yB (dead before yB's first real write)
    float* out1k  = yB;                    // 512*512*20
    float* keyT   = yB + 5242880;          // 512*16*512
    float* q1     = keyT + 4194304;        // 512*512*5
    float* queryT = q1 + 1310720;          // 512*512
    float* attw   = queryT + 262144;       // 512*16

    dct_kernel<<<2, 384, 0, stream>>>(dct20);

    conv1_relu<25, 0, 20><<<BSZ, 256, 0, stream>>>(src, Wk1, out1k);
    conv2_gemm<20, 16><<<dim3(128, 8), 256, 0, stream>>>(out1k, Wk2, keyT);
    conv1_relu<10, 40, 5><<<BSZ, 256, 0, stream>>>(src, Wq1, q1);
    conv2_gemm<5, 1><<<dim3(8, 8), 256, 0, stream>>>(q1, Wq2, queryT);
    att_kernel<<<BSZ, 256, 0, stream>>>(queryT, keyT, attw);
    xbuild<<<BSZ, 256, 0, stream>>>(src, attw, dct20, xb);

    // gc1
    gemm_k40<<<8448, 256, 0, stream>>>(xb, gc1_W, tb);
    amult_bn_tanh<<<BSZ * 4, 256, 0, stream>>>(tb, gc1_att, gc1_b, bn1_g, bn1_b,
                                               nullptr, yA);
    // stages
    for (int st = 0; st < 2; ++st) {
        const float* W0  = gcb_W + (size_t)(st * 2 + 0) * 262144;
        const float* W1  = gcb_W + (size_t)(st * 2 + 1) * 262144;
        const float* A0  = gcb_att + (size_t)(st * 2 + 0) * 4356;
        const float* A1  = gcb_att + (size_t)(st * 2 + 1) * 4356;
        const float* b0  = gcb_b + (size_t)(st * 2 + 0) * 512;
        const float* b1  = gcb_b + (size_t)(st * 2 + 1) * 512;
        const float* g0  = gcb_g + (size_t)(st * 2 + 0) * 33792;
        const float* g1  = gcb_g + (size_t)(st * 2 + 1) * 33792;
        const float* be0 = gcb_be + (size_t)(st * 2 + 0) * 33792;
        const float* be1 = gcb_be + (size_t)(st * 2 + 1) * 33792;
        gemm_tiled<<<dim3(528, 8), 256, 0, stream>>>(yA, W0, tb, 512, 512);
        amult_bn_tanh<<<BSZ * 4, 256, 0, stream>>>(tb, A0, b0, g0, be0, nullptr, yB);
        gemm_tiled<<<dim3(528, 8), 256, 0, stream>>>(yB, W1, tb, 512, 512);
        amult_bn_tanh<<<BSZ * 4, 256, 0, stream>>>(tb, A1, b1, g1, be1, yA, yA);
    }
    // gc7 (only first 20 output features needed) + final IDCT
    gemm_n20<<<4224, 256, 0, stream>>>(yA, gc7_W, tb);
    gc7_amult<<<BSZ, 256, 0, stream>>>(tb, gc7_att, gc7_b, xb, dctout);
    final_out<<<BSZ, 256, 0, stream>>>(dctout, dct20, out);
}

// Round 2
// 1033.964 us; speedup vs baseline: 2.5740x; 2.5740x over previous
//
#include <hip/hip_runtime.h>
#include <math.h>

#define PI_D 3.14159265358979323846

#define BSZ   512
#define NODE  66
#define HID   512
#define VL    35
#define DCTN  20

static constexpr float BN_INVS = 0.99999500003749969f; // 1/sqrt(1+1e-5)

typedef unsigned short u16;
using bf16x8 = __attribute__((ext_vector_type(8))) short;
using f32x4  = __attribute__((ext_vector_type(4))) float;

__device__ inline u16 f2bf(float f) {
    union { float f; unsigned int u; } v; v.f = f;
    unsigned int r = v.u + 0x7FFFu + ((v.u >> 16) & 1u);
    return (u16)(r >> 16);
}
__device__ inline float bf2f(u16 b) {
    union { unsigned int u; float f; } v; v.u = ((unsigned int)b) << 16;
    return v.f;
}

// ---------------- dct20 (20 x 35), orthonormal DCT-II rows ----------------
__global__ void dct_kernel(float* __restrict__ dct20) {
    int i = blockIdx.x * blockDim.x + threadIdx.x;
    if (i < DCTN * VL) {
        int k = i / VL, v = i - k * VL;
        double w = (k == 0) ? sqrt(1.0 / VL) : sqrt(2.0 / VL);
        dct20[i] = (float)(w * cos(PI_D * (v + 0.5) * k / (double)VL));
    }
}

// ---------------- weight conversion / transpose to bf16 ----------------
// gcb_W (4,512,512)[l][k][n] -> Wt[l][n][k]
__global__ void cvt_gcb(const float* __restrict__ W, u16* __restrict__ Wt) {
    int l = blockIdx.y;
    int i = blockIdx.x * 256 + threadIdx.x;      // n*512+k
    int n = i >> 9, k = i & 511;
    Wt[(size_t)l * 262144 + i] = f2bf(W[(size_t)l * 262144 + (size_t)k * 512 + n]);
}
// gc1_W (40,512) -> Wt[n=0..511][k=0..63] (zero pad k>=40)
__global__ void cvt_gc1(const float* __restrict__ W, u16* __restrict__ Wt) {
    int i = blockIdx.x * 256 + threadIdx.x;      // 512*64
    int n = i >> 6, k = i & 63;
    Wt[i] = (k < 40) ? f2bf(W[k * 512 + n]) : (u16)0;
}
// gc7_W (512,40) -> Wt[n=0..127][k=0..511] (only n<20 valid, rest zero)
__global__ void cvt_gc7(const float* __restrict__ W, u16* __restrict__ Wt) {
    int i = blockIdx.x * 256 + threadIdx.x;      // 128*512
    int n = i >> 9, k = i & 511;
    Wt[i] = (n < 20) ? f2bf(W[k * 40 + n]) : (u16)0;
}
// conv1 W (512,66,6) -> Wt[d][k=h*66+c], K=416 (zero pad k>=396)
__global__ void cvt_w1(const float* __restrict__ W, u16* __restrict__ Wt) {
    int i = blockIdx.x * 256 + threadIdx.x;      // 512*416
    int d = i / 416, k = i - d * 416;
    float v = 0.f;
    if (k < 396) { int h = k / 66, c = k - h * 66; v = W[d * 396 + c * 6 + h]; }
    Wt[i] = f2bf(v);
}
// conv2 W (512,512,5) -> Wt[d][k=h*512+c]
__global__ void cvt_w2(const float* __restrict__ W, u16* __restrict__ Wt) {
    int i = blockIdx.x * 256 + threadIdx.x;      // 512*2560
    int d = i / 2560, k = i - d * 2560;
    int h = k >> 9, c = k & 511;
    Wt[i] = f2bf(W[(size_t)d * 2560 + c * 5 + h]);
}

// ---------------- im2col for conv1 from src ----------------
// A[(b*TOUT+t)][h*66+c] = src[b][(T0+t+h)][c] * 1e-3, K=416 zero-padded
template<int TOUT, int T0>
__global__ void im2col_src(const float* __restrict__ src, u16* __restrict__ A) {
    int R = blockIdx.x;
    int b = R / TOUT, t = R - b * TOUT;
    const float* s = src + (size_t)b * 3300 + (T0 + t) * 66;
    u16* a = A + (size_t)R * 416;
    for (int k = threadIdx.x; k < 416; k += 256) {
        float v = 0.f;
        if (k < 396) { int h = k / 66, c = k - h * 66; v = s[h * 66 + c] * 1e-3f; }
        a[k] = f2bf(v);
    }
}

// ---------------- im2col for conv2-key from key1 (b,20,512) bf16 ----------------
// Aim[(b*16+t)][h*512+c] = key1[b][(t+h)][c]
__global__ void im2col_k2(const u16* __restrict__ key1, u16* __restrict__ Aim) {
    size_t i = (size_t)blockIdx.x * 256 + threadIdx.x;   // 8-elem chunk id, total 8192*320
    int k8 = (int)(i % 320); int bt = (int)(i / 320);
    int t = bt & 15, b = bt >> 4;
    int k = k8 * 8;
    int h = k >> 9, c = k & 511;
    *(bf16x8*)(Aim + i * 8) = *(const bf16x8*)(key1 + ((size_t)b * 20 + t + h) * 512 + c);
}

// ---------------- generic bf16 MFMA GEMM ----------------
// C[M,Nvalid] = A[M,K] @ Bt[N,K]^T ; A row-major bf16 (lda=K), Bt row-major bf16 [n][k]
// BM=128, BN=128, BK=32; 256 thr = 4 waves (2x2), wave = 64x64, 4x4 frags of 16x16.
template<bool RELU, bool OUTBF>
__global__ __launch_bounds__(256) void gemm_bf16(const u16* __restrict__ A,
                                                 const u16* __restrict__ Bt,
                                                 void* __restrict__ Cout,
                                                 int M, int K, int Nvalid, int ldc) {
    __shared__ u16 As[128][40];
    __shared__ u16 Bs[128][40];
    const int tid = threadIdx.x;
    const int r0 = blockIdx.x * 128, n0 = blockIdx.y * 128;
    const int lane = tid & 63, w = tid >> 6;
    const int wr = (w >> 1) * 64, wc = (w & 1) * 64;
    const int row16 = lane & 15, grp = lane >> 4;
    const int sr = tid >> 1, sq = (tid & 1) * 16;
    const u16* ap = A + (size_t)(r0 + sr) * K + sq;
    const u16* bp = Bt + (size_t)(n0 + sr) * K + sq;
    f32x4 acc[4][4] = {};
    for (int k0 = 0; k0 < K; k0 += 32) {
        *(bf16x8*)&As[sr][sq]     = *(const bf16x8*)(ap + k0);
        *(bf16x8*)&As[sr][sq + 8] = *(const bf16x8*)(ap + k0 + 8);
        *(bf16x8*)&Bs[sr][sq]     = *(const bf16x8*)(bp + k0);
        *(bf16x8*)&Bs[sr][sq + 8] = *(const bf16x8*)(bp + k0 + 8);
        __syncthreads();
        bf16x8 a[4], b[4];
#pragma unroll
        for (int m = 0; m < 4; ++m) a[m] = *(const bf16x8*)&As[wr + m * 16 + row16][grp * 8];
#pragma unroll
        for (int n = 0; n < 4; ++n) b[n] = *(const bf16x8*)&Bs[wc + n * 16 + row16][grp * 8];
#pragma unroll
        for (int m = 0; m < 4; ++m)
#pragma unroll
            for (int n = 0; n < 4; ++n)
                acc[m][n] = __builtin_amdgcn_mfma_f32_16x16x32_bf16(a[m], b[n], acc[m][n], 0, 0, 0);
        __syncthreads();
    }
#pragma unroll
    for (int m = 0; m < 4; ++m) {
        int r = r0 + wr + m * 16 + grp * 4;
#pragma unroll
        for (int n = 0; n < 4; ++n) {
            int c = n0 + wc + n * 16 + row16;
            if (c < Nvalid) {
#pragma unroll
                for (int j = 0; j < 4; ++j) {
                    float v = acc[m][n][j];
                    if (RELU) v = fmaxf(v, 0.f);
                    if (OUTBF) ((u16*)Cout)[(size_t)(r + j) * ldc + c] = f2bf(v);
                    else       ((float*)Cout)[(size_t)(r + j) * ldc + c] = v;
                }
            }
        }
    }
}

// ---------------- attention weights: att[b,n] ----------------
__global__ __launch_bounds__(256) void att_kernel(const float* __restrict__ qT,
                                                  const float* __restrict__ kT,
                                                  float* __restrict__ att) {
    const int b = blockIdx.x, tid = threadIdx.x;
    __shared__ float part[256];
    __shared__ float sc[16];
    int n = tid >> 4, j = tid & 15;
    const float* q = qT + b * 512;
    const float* k = kT + b * 8192 + n * 512;
    float acc = 0.f;
    for (int d = j; d < 512; d += 16) acc += q[d] * k[d];
    part[tid] = acc;
    __syncthreads();
    if (tid < 16) {
        float s = 0.f;
        for (int jj = 0; jj < 16; ++jj) s += part[tid * 16 + jj];
        sc[tid] = s + 1e-15f;
    }
    __syncthreads();
    if (tid == 0) {
        float tot = 0.f;
        for (int nn = 0; nn < 16; ++nn) tot += sc[nn];
        float inv = 1.f / tot;
        for (int nn = 0; nn < 16; ++nn) att[b * 16 + nn] = sc[nn] * inv;
    }
}

// ---------------- build x : fp32 (b,66,40) + bf16 padded (b,66,64) ----------------
__global__ __launch_bounds__(256) void xbuild(const float* __restrict__ src,
                                              const float* __restrict__ att,
                                              const float* __restrict__ dct20,
                                              float* __restrict__ x,
                                              u16* __restrict__ xbf) {
    const int b = blockIdx.x, tid = threadIdx.x;
    __shared__ float s_src[50 * 66];
    __shared__ float s_sacc[VL * 66];
    __shared__ float s_d[DCTN * VL];
    __shared__ float s_att[16];
    for (int i = tid; i < 3300; i += 256) s_src[i] = src[b * 3300 + i];
    for (int i = tid; i < DCTN * VL; i += 256) s_d[i] = dct20[i];
    if (tid < 16) s_att[tid] = att[b * 16 + tid];
    __syncthreads();
    for (int i = tid; i < VL * 66; i += 256) {
        int v = i / 66, f = i - v * 66;
        float a = 0.f;
#pragma unroll
        for (int n = 0; n < 16; ++n) a += s_att[n] * s_src[(n + v) * 66 + f];
        s_sacc[i] = a;
    }
    __syncthreads();
    for (int i = tid; i < 66 * DCTN; i += 256) {
        int f = i / DCTN, kq = i - (i / DCTN) * DCTN;
        float din = 0.f, datt = 0.f;
        for (int v = 0; v < VL; ++v) {
            float dv = s_d[kq * VL + v];
            int t2 = (v < 10) ? (40 + v) : 49;
            din += dv * s_src[t2 * 66 + f];
            datt += dv * s_sacc[v * 66 + f];
        }
        x[b * 2640 + f * 40 + kq] = din;
        x[b * 2640 + f * 40 + 20 + kq] = datt;
        xbf[(size_t)b * 4224 + f * 64 + kq] = f2bf(din);
        xbf[(size_t)b * 4224 + f * 64 + 20 + kq] = f2bf(datt);
    }
    for (int i = tid; i < 66 * 24; i += 256) {
        int f = i / 24, kp = 40 + (i - (i / 24) * 24);
        xbf[(size_t)b * 4224 + f * 64 + kp] = 0;
    }
}

// ---------------- A-mult + bias + bn + tanh (+residual), bf16 y ----------------
__global__ __launch_bounds__(256) void amult_bn_tanh(const float* __restrict__ t,
                                                     const float* __restrict__ A,
                                                     const float* __restrict__ bias,
                                                     const float* __restrict__ g,
                                                     const float* __restrict__ be,
                                                     const u16* __restrict__ yres,
                                                     u16* __restrict__ yout) {
    const int b = blockIdx.x >> 2;
    const int f0 = (blockIdx.x & 3) * 128;
    const int tid = threadIdx.x;
    __shared__ float ts[66][128];
    __shared__ float As[4752];
    for (int i = tid; i < 66 * 128; i += 256) {
        int m = i >> 7, f = i & 127;
        ts[m][f] = t[(size_t)b * 33792 + m * 512 + f0 + f];
    }
    for (int i = tid; i < 4356; i += 256) As[i] = A[i];
    __syncthreads();
    for (int task = tid; task < 288; task += 256) {
        int q = task & 31;
        int n0 = (task >> 5) * 8;
        float acc[8][4] = {};
        for (int m = 0; m < 66; ++m) {
            float4 tv = *(const float4*)&ts[m][q * 4];
#pragma unroll
            for (int i = 0; i < 8; ++i) {
                float a = As[(n0 + i) * 66 + m];
                acc[i][0] += a * tv.x;
                acc[i][1] += a * tv.y;
                acc[i][2] += a * tv.z;
                acc[i][3] += a * tv.w;
            }
        }
#pragma unroll
        for (int i = 0; i < 8; ++i) {
            int n = n0 + i;
            if (n < 66) {
#pragma unroll
                for (int j = 0; j < 4; ++j) {
                    int f = f0 + q * 4 + j;
                    int gi = n * 512 + f;
                    float z = acc[i][j] + bias[f];
                    float v = tanhf(z * (g[gi] * BN_INVS) + be[gi]);
                    if (yres) v += bf2f(yres[(size_t)b * 33792 + gi]);
                    yout[(size_t)b * 33792 + gi] = f2bf(v);
                }
            }
        }
    }
}

// ---------------- dctout[b,n,c] = sum_m A7[n,m]*t2[b,m,c] + b7[c] + x[b,n,c] --
__global__ __launch_bounds__(256) void gc7_amult(const float* __restrict__ t2,
                                                 const float* __restrict__ A7,
                                                 const float* __restrict__ b7,
                                                 const float* __restrict__ x,
                                                 float* __restrict__ dctout) {
    const int b = blockIdx.x, tid = threadIdx.x;
    __shared__ float ts[66 * 20];
    __shared__ float As[66 * 66];
    for (int i = tid; i < 1320; i += 256) ts[i] = t2[(size_t)b * 1320 + i];
    for (int i = tid; i < 4356; i += 256) As[i] = A7[i];
    __syncthreads();
    for (int o = tid; o < 1320; o += 256) {
        int n = o / 20, c = o - (o / 20) * 20;
        float acc = b7[c] + x[(size_t)b * 2640 + n * 40 + c];
        for (int m = 0; m < 66; ++m) acc += As[n * 66 + m] * ts[m * 20 + c];
        dctout[(size_t)b * 1320 + o] = acc;
    }
}

// ---------------- out[b,v,f] = sum_k dct20[k,v]*dctout[b,f,k] ----------------
__global__ __launch_bounds__(256) void final_out(const float* __restrict__ dctout,
                                                 const float* __restrict__ dct20,
                                                 float* __restrict__ out) {
    const int b = blockIdx.x, tid = threadIdx.x;
    __shared__ float ds[DCTN * VL];
    __shared__ float dos[66 * 20];
    for (int i = tid; i < DCTN * VL; i += 256) ds[i] = dct20[i];
    for (int i = tid; i < 1320; i += 256) dos[i] = dctout[(size_t)b * 1320 + i];
    __syncthreads();
    for (int o = tid; o < VL * 66; o += 256) {
        int v = o / 66, f = o - (o / 66) * 66;
        float acc = 0.f;
#pragma unroll
        for (int k = 0; k < DCTN; ++k) acc += ds[k * VL + v] * dos[f * 20 + k];
        out[(size_t)b * 2310 + o] = acc;
    }
}

extern "C" void kernel_launch(void* const* d_in, const int* in_sizes, int n_in,
                              void* d_out, int out_size, void* d_ws, size_t ws_size,
                              hipStream_t stream) {
    const float* src     = (const float*)d_in[0];
    const float* Wq1     = (const float*)d_in[1];
    const float* Wq2     = (const float*)d_in[2];
    const float* Wk1     = (const float*)d_in[3];
    const float* Wk2     = (const float*)d_in[4];
    const float* gc1_W   = (const float*)d_in[5];
    const float* gc1_att = (const float*)d_in[6];
    const float* gc1_b   = (const float*)d_in[7];
    const float* bn1_g   = (const float*)d_in[8];
    const float* bn1_b   = (const float*)d_in[9];
    const float* gcb_W   = (const float*)d_in[10];
    const float* gcb_att = (const float*)d_in[11];
    const float* gcb_b   = (const float*)d_in[12];
    const float* gcb_g   = (const float*)d_in[13];
    const float* gcb_be  = (const float*)d_in[14];
    const float* gc7_W   = (const float*)d_in[15];
    const float* gc7_att = (const float*)d_in[16];
    const float* gc7_b   = (const float*)d_in[17];
    float* out = (float*)d_out;

    unsigned char* base = (unsigned char*)d_ws;
    size_t off = 0;
    auto take = [&](size_t bytes) -> void* {
        void* p = base + off;
        off += (bytes + 255) & ~(size_t)255;
        return p;
    };
    u16*   yA     = (u16*)take((size_t)33792 * 512 * 2);
    u16*   yB     = (u16*)take((size_t)33792 * 512 * 2);
    float* tb     = (float*)take((size_t)33792 * 512 * 4);
    float* xb     = (float*)take((size_t)512 * 2640 * 4);
    u16*   xbf    = (u16*)take((size_t)512 * 4224 * 2);
    float* dct20  = (float*)take(2800);
    float* dctout = (float*)take((size_t)512 * 1320 * 4);
    u16*   key1   = (u16*)take((size_t)512 * 20 * 512 * 2);
    u16*   q1     = (u16*)take((size_t)512 * 5 * 512 * 2);
    float* keyT   = (float*)take((size_t)8192 * 512 * 4);
    float* queryT = (float*)take((size_t)512 * 512 * 4);
    float* attw   = (float*)take((size_t)512 * 16 * 4);
    u16*   WtGcb  = (u16*)take((size_t)4 * 512 * 512 * 2);
    u16*   WtGc1  = (u16*)take((size_t)512 * 64 * 2);
    u16*   WtGc7  = (u16*)take((size_t)128 * 512 * 2);
    u16*   WtW1k  = (u16*)take((size_t)512 * 416 * 2);
    u16*   WtW1q  = (u16*)take((size_t)512 * 416 * 2);
    u16*   WtW2k  = (u16*)take((size_t)512 * 2560 * 2);
    u16*   WtW2q  = (u16*)take((size_t)512 * 2560 * 2);
    // early-phase aliases inside tb (dead before tb's first write in gc1 gemm)
    u16* A1k   = (u16*)tb;                         // 10240*416
    u16* A1q   = A1k + (size_t)10240 * 416;        // 2560*416
    u16* Aim2k = A1q + (size_t)2560 * 416;         // 8192*2560

    dct_kernel<<<2, 384, 0, stream>>>(dct20);
    cvt_gcb<<<dim3(1024, 4), 256, 0, stream>>>(gcb_W, WtGcb);
    cvt_gc1<<<128, 256, 0, stream>>>(gc1_W, WtGc1);
    cvt_gc7<<<256, 256, 0, stream>>>(gc7_W, WtGc7);
    cvt_w1<<<832, 256, 0, stream>>>(Wk1, WtW1k);
    cvt_w1<<<832, 256, 0, stream>>>(Wq1, WtW1q);
    cvt_w2<<<5120, 256, 0, stream>>>(Wk2, WtW2k);
    cvt_w2<<<5120, 256, 0, stream>>>(Wq2, WtW2q);

    im2col_src<20, 0><<<10240, 256, 0, stream>>>(src, A1k);
    im2col_src<5, 40><<<2560, 256, 0, stream>>>(src, A1q);
    gemm_bf16<true, true><<<dim3(80, 4), 256, 0, stream>>>(A1k, WtW1k, key1, 10240, 416, 512, 512);
    gemm_bf16<true, true><<<dim3(20, 4), 256, 0, stream>>>(A1q, WtW1q, q1, 2560, 416, 512, 512);
    im2col_k2<<<10240, 256, 0, stream>>>(key1, Aim2k);
    gemm_bf16<true, false><<<dim3(64, 4), 256, 0, stream>>>(Aim2k, WtW2k, keyT, 8192, 2560, 512, 512);
    gemm_bf16<true, false><<<dim3(4, 4), 256, 0, stream>>>(q1, WtW2q, queryT, 512, 2560, 512, 512);
    att_kernel<<<BSZ, 256, 0, stream>>>(queryT, keyT, attw);
    xbuild<<<BSZ, 256, 0, stream>>>(src, attw, dct20, xb, xbf);

    // gc1
    gemm_bf16<false, false><<<dim3(264, 4), 256, 0, stream>>>(xbf, WtGc1, tb, 33792, 64, 512, 512);
    amult_bn_tanh<<<BSZ * 4, 256, 0, stream>>>(tb, gc1_att, gc1_b, bn1_g, bn1_b, nullptr, yA);
    // stages
    for (int st = 0; st < 2; ++st) {
        const u16*   W0  = WtGcb + (size_t)(st * 2 + 0) * 262144;
        const u16*   W1  = WtGcb + (size_t)(st * 2 + 1) * 262144;
        const float* A0  = gcb_att + (size_t)(st * 2 + 0) * 4356;
        const float* A1  = gcb_att + (size_t)(st * 2 + 1) * 4356;
        const float* b0  = gcb_b + (size_t)(st * 2 + 0) * 512;
        const float* b1  = gcb_b + (size_t)(st * 2 + 1) * 512;
        const float* g0  = gcb_g + (size_t)(st * 2 + 0) * 33792;
        const float* g1  = gcb_g + (size_t)(st * 2 + 1) * 33792;
        const float* be0 = gcb_be + (size_t)(st * 2 + 0) * 33792;
        const float* be1 = gcb_be + (size_t)(st * 2 + 1) * 33792;
        gemm_bf16<false, false><<<dim3(264, 4), 256, 0, stream>>>(yA, W0, tb, 33792, 512, 512, 512);
        amult_bn_tanh<<<BSZ * 4, 256, 0, stream>>>(tb, A0, b0, g0, be0, nullptr, yB);
        gemm_bf16<false, false><<<dim3(264, 4), 256, 0, stream>>>(yB, W1, tb, 33792, 512, 512, 512);
        amult_bn_tanh<<<BSZ * 4, 256, 0, stream>>>(tb, A1, b1, g1, be1, yA, yA);
    }
    // gc7 (only first 20 output cols) + final IDCT
    gemm_bf16<false, false><<<dim3(264, 1), 256, 0, stream>>>(yA, WtGc7, tb, 33792, 512, 20, 20);
    gc7_amult<<<BSZ, 256, 0, stream>>>(tb, gc7_att, gc7_b, xb, dctout);
    final_out<<<BSZ, 256, 0, stream>>>(dctout, dct20, out);
}

// Round 3
// 844.077 us; speedup vs baseline: 3.1531x; 1.2250x over previous
//
#include <hip/hip_runtime.h>
#include <math.h>

#define PI_D 3.14159265358979323846

#define BSZ   512
#define NODE  66
#define VL    35
#define DCTN  20

static constexpr float BN_INVS = 0.99999500003749969f; // 1/sqrt(1+1e-5)

typedef unsigned short u16;
using bf16x8 = __attribute__((ext_vector_type(8))) short;
using f32x4  = __attribute__((ext_vector_type(4))) float;

__device__ inline u16 f2bf(float f) {
    union { float f; unsigned int u; } v; v.f = f;
    unsigned int r = v.u + 0x7FFFu + ((v.u >> 16) & 1u);
    return (u16)(r >> 16);
}
__device__ inline float bf2f(u16 b) {
    union { unsigned int u; float f; } v; v.u = ((unsigned int)b) << 16;
    return v.f;
}

// ---------------- dct20 (20 x 35), orthonormal DCT-II rows ----------------
__global__ void dct_kernel(float* __restrict__ dct20) {
    int i = blockIdx.x * blockDim.x + threadIdx.x;
    if (i < DCTN * VL) {
        int k = i / VL, v = i - k * VL;
        double w = (k == 0) ? sqrt(1.0 / VL) : sqrt(2.0 / VL);
        dct20[i] = (float)(w * cos(PI_D * (v + 0.5) * k / (double)VL));
    }
}

// ---------------- weight conversion / transpose to bf16 ----------------
// gcb_W (4,512,512)[l][k][n] -> Wt[l][n][k]
__global__ void cvt_gcb(const float* __restrict__ W, u16* __restrict__ Wt) {
    int l = blockIdx.y;
    int i = blockIdx.x * 256 + threadIdx.x;
    int n = i >> 9, k = i & 511;
    Wt[(size_t)l * 262144 + i] = f2bf(W[(size_t)l * 262144 + (size_t)k * 512 + n]);
}
// gc1_W (40,512) -> Wt[n=0..511][k=0..63] (zero pad k>=40)
__global__ void cvt_gc1(const float* __restrict__ W, u16* __restrict__ Wt) {
    int i = blockIdx.x * 256 + threadIdx.x;
    int n = i >> 6, k = i & 63;
    Wt[i] = (k < 40) ? f2bf(W[k * 512 + n]) : (u16)0;
}
// gc7_W (512,40) -> Wt[n=0..127][k=0..511] (only n<20 valid, rest zero)
__global__ void cvt_gc7(const float* __restrict__ W, u16* __restrict__ Wt) {
    int i = blockIdx.x * 256 + threadIdx.x;
    int n = i >> 9, k = i & 511;
    Wt[i] = (n < 20) ? f2bf(W[k * 40 + n]) : (u16)0;
}
// conv1 W (512,66,6) -> Wt[d][k=h*66+c], K=416 (zero pad k>=396)
__global__ void cvt_w1(const float* __restrict__ W, u16* __restrict__ Wt) {
    int i = blockIdx.x * 256 + threadIdx.x;
    int d = i / 416, k = i - d * 416;
    float v = 0.f;
    if (k < 396) { int h = k / 66, c = k - h * 66; v = W[d * 396 + c * 6 + h]; }
    Wt[i] = f2bf(v);
}
// conv2 W (512,512,5) -> Wt[d][k=h*512+c]
__global__ void cvt_w2(const float* __restrict__ W, u16* __restrict__ Wt) {
    int i = blockIdx.x * 256 + threadIdx.x;
    int d = i / 2560, k = i - d * 2560;
    int h = k >> 9, c = k & 511;
    Wt[i] = f2bf(W[(size_t)d * 2560 + c * 5 + h]);
}
// A matrices (66x66) -> prepadded bf16 [6][80][104]
__global__ void cvt_att(const float* __restrict__ gc1A, const float* __restrict__ gcbA,
                        const float* __restrict__ gc7A, u16* __restrict__ Abf) {
    int l = blockIdx.y;
    int i = blockIdx.x * 256 + threadIdx.x;
    if (i < 8320) {
        int r = i / 104, c = i - (i / 104) * 104;
        float v = 0.f;
        if (r < 66 && c < 66) {
            const float* A = (l == 0) ? gc1A : (l <= 4 ? gcbA + (size_t)(l - 1) * 4356 : gc7A);
            v = A[r * 66 + c];
        }
        Abf[(size_t)l * 8320 + i] = f2bf(v);
    }
}

// ---------------- amul: U[b] = A(80x96pad) @ Y[b](66xNW), bf16 MFMA ----------
// Abf prepadded [80][104]; Y row-major [b][66][NW]; U [b][66][NW]
template<int FB, int NW>
__global__ __launch_bounds__(256) void amul(const u16* __restrict__ Y,
                                            const u16* __restrict__ Abf,
                                            u16* __restrict__ U) {
    const int b = blockIdx.x, f0 = blockIdx.y * FB;
    const int tid = threadIdx.x;
    __shared__ u16 As[80][104];
    __shared__ u16 Ys[FB][104];
    for (int i = tid; i < 4160; i += 256) ((unsigned int*)As)[i] = ((const unsigned int*)Abf)[i];
    for (int i = tid; i < 66 * (FB / 2); i += 256) {
        int m = i / (FB / 2), fi = i - (i / (FB / 2)) * (FB / 2);
        unsigned int v = *(const unsigned int*)&Y[((size_t)b * 66 + m) * NW + f0 + 2 * fi];
        Ys[2 * fi][m] = (u16)(v & 0xffff);
        Ys[2 * fi + 1][m] = (u16)(v >> 16);
    }
    for (int i = tid; i < FB * 19; i += 256) {
        int f = i / 19, j = i - (i / 19) * 19;
        ((unsigned int*)&Ys[f][66])[j] = 0;
    }
    __syncthreads();
    const int lane = tid & 63, w = tid >> 6;
    const int row16 = lane & 15, grp = lane >> 4;
    const int fbase = w * (FB / 4);
    constexpr int NFT = FB / 64;  // f-tiles per wave (2 for FB=128, 1 for FB=64)
    f32x4 acc[5][NFT] = {};
#pragma unroll
    for (int k0 = 0; k0 < 96; k0 += 32) {
        bf16x8 aF[5], bF[NFT];
#pragma unroll
        for (int mt = 0; mt < 5; ++mt) aF[mt] = *(const bf16x8*)&As[mt * 16 + row16][grp * 8 + k0];
#pragma unroll
        for (int ft = 0; ft < NFT; ++ft) bF[ft] = *(const bf16x8*)&Ys[fbase + ft * 16 + row16][grp * 8 + k0];
#pragma unroll
        for (int mt = 0; mt < 5; ++mt)
#pragma unroll
            for (int ft = 0; ft < NFT; ++ft)
                acc[mt][ft] = __builtin_amdgcn_mfma_f32_16x16x32_bf16(aF[mt], bF[ft], acc[mt][ft], 0, 0, 0);
    }
#pragma unroll
    for (int mt = 0; mt < 5; ++mt) {
#pragma unroll
        for (int ft = 0; ft < NFT; ++ft) {
            int fcol = f0 + fbase + ft * 16 + row16;
#pragma unroll
            for (int j = 0; j < 4; ++j) {
                int row = mt * 16 + grp * 4 + j;
                if (row < 66)
                    U[((size_t)b * 66 + row) * NW + fcol] = f2bf(acc[mt][ft][j]);
            }
        }
    }
}

// ---------------- unified bf16 MFMA GEMM with fused epilogues ----------------
// C[M,Nvalid] = Asrc[M,K] @ Bt[N,K]^T
// ASRC: 0 = bf16 row-major lda=K; 1 = bf16 conv window (in[b][TIN][512], k-contig);
//       2 = fp32 src window (src[b][50][66], base (T0+t)*66, k<396 guard, *1e-3)
// EPI:  0 = relu -> bf16 (ldc); 1 = relu -> fp32 (ldc);
//       2 = bn+tanh -> bf16 y;  3 = bn+tanh+res -> bf16 y;
//       4 = +bias +x -> fp32 dctout (Nvalid=20)
template<int ASRC, int EPI, int TOUT, int TIN, int T0>
__global__ __launch_bounds__(256) void gemm_uni(const void* __restrict__ Asrc,
                                                const u16* __restrict__ Bt,
                                                void* __restrict__ Cout,
                                                int M, int K, int Nvalid, int ldc,
                                                const float* __restrict__ bias,
                                                const float* __restrict__ g,
                                                const float* __restrict__ be,
                                                const u16* __restrict__ yres,
                                                const float* __restrict__ xres) {
    __shared__ u16 As[128][40];
    __shared__ u16 Bs[128][40];
    const int tid = threadIdx.x;
    const int r0 = blockIdx.x * 128, n0 = blockIdx.y * 128;
    const int lane = tid & 63, w = tid >> 6;
    const int wr = (w >> 1) * 64, wc = (w & 1) * 64;
    const int row16 = lane & 15, grp = lane >> 4;
    const int sr = tid >> 1, sq = (tid & 1) * 16;

    const u16* ap = nullptr;
    const float* apf = nullptr;
    if constexpr (ASRC == 0) {
        ap = (const u16*)Asrc + (size_t)(r0 + sr) * K + sq;
    } else if constexpr (ASRC == 1) {
        int R = r0 + sr; int b = R / TOUT, t = R - b * TOUT;
        ap = (const u16*)Asrc + ((size_t)b * TIN + t) * 512 + sq;
    } else {
        int R = r0 + sr; int b = R / TOUT, t = R - b * TOUT;
        apf = (const float*)Asrc + (size_t)b * 3300 + (T0 + t) * 66 + sq;
    }
    const u16* bp = Bt + (size_t)(n0 + sr) * K + sq;

    f32x4 acc[4][4] = {};
    for (int k0 = 0; k0 < K; k0 += 32) {
        if constexpr (ASRC <= 1) {
            *(bf16x8*)&As[sr][sq]     = *(const bf16x8*)(ap + k0);
            *(bf16x8*)&As[sr][sq + 8] = *(const bf16x8*)(ap + k0 + 8);
        } else {
#pragma unroll
            for (int j = 0; j < 16; ++j) {
                int k = k0 + sq + j;
                float vin = 0.f;
                if (k < 396) vin = apf[k0 + j];
                As[sr][sq + j] = f2bf(vin * 1e-3f);
            }
        }
        *(bf16x8*)&Bs[sr][sq]     = *(const bf16x8*)(bp + k0);
        *(bf16x8*)&Bs[sr][sq + 8] = *(const bf16x8*)(bp + k0 + 8);
        __syncthreads();
        bf16x8 a[4], b[4];
#pragma unroll
        for (int m = 0; m < 4; ++m) a[m] = *(const bf16x8*)&As[wr + m * 16 + row16][grp * 8];
#pragma unroll
        for (int n = 0; n < 4; ++n) b[n] = *(const bf16x8*)&Bs[wc + n * 16 + row16][grp * 8];
#pragma unroll
        for (int m = 0; m < 4; ++m)
#pragma unroll
            for (int n = 0; n < 4; ++n)
                acc[m][n] = __builtin_amdgcn_mfma_f32_16x16x32_bf16(a[m], b[n], acc[m][n], 0, 0, 0);
        __syncthreads();
    }
#pragma unroll
    for (int m = 0; m < 4; ++m) {
        int rb = r0 + wr + m * 16 + grp * 4;
#pragma unroll
        for (int n = 0; n < 4; ++n) {
            int c = n0 + wc + n * 16 + row16;
            if (c < Nvalid) {
#pragma unroll
                for (int j = 0; j < 4; ++j) {
                    int row = rb + j;
                    float v = acc[m][n][j];
                    if constexpr (EPI == 0) {
                        ((u16*)Cout)[(size_t)row * ldc + c] = f2bf(fmaxf(v, 0.f));
                    } else if constexpr (EPI == 1) {
                        ((float*)Cout)[(size_t)row * ldc + c] = fmaxf(v, 0.f);
                    } else if constexpr (EPI == 2 || EPI == 3) {
                        int bb = row / 66, nn = row - bb * 66;
                        int gi = nn * 512 + c;
                        float z = v + bias[c];
                        float t = tanhf(z * (g[gi] * BN_INVS) + be[gi]);
                        if constexpr (EPI == 3) t += bf2f(yres[(size_t)row * 512 + c]);
                        ((u16*)Cout)[(size_t)row * 512 + c] = f2bf(t);
                    } else {
                        int bb = row / 66, nn = row - bb * 66;
                        ((float*)Cout)[(size_t)bb * 1320 + nn * 20 + c] =
                            v + bias[c] + xres[(size_t)bb * 2640 + nn * 40 + c];
                    }
                }
            }
        }
    }
}

// ---------------- attention weights: att[b,n] ----------------
__global__ __launch_bounds__(256) void att_kernel(const float* __restrict__ qT,
                                                  const float* __restrict__ kT,
                                                  float* __restrict__ att) {
    const int b = blockIdx.x, tid = threadIdx.x;
    __shared__ float part[256];
    __shared__ float sc[16];
    int n = tid >> 4, j = tid & 15;
    const float* q = qT + b * 512;
    const float* k = kT + b * 8192 + n * 512;
    float acc = 0.f;
    for (int d = j; d < 512; d += 16) acc += q[d] * k[d];
    part[tid] = acc;
    __syncthreads();
    if (tid < 16) {
        float s = 0.f;
        for (int jj = 0; jj < 16; ++jj) s += part[tid * 16 + jj];
        sc[tid] = s + 1e-15f;
    }
    __syncthreads();
    if (tid == 0) {
        float tot = 0.f;
        for (int nn = 0; nn < 16; ++nn) tot += sc[nn];
        float inv = 1.f / tot;
        for (int nn = 0; nn < 16; ++nn) att[b * 16 + nn] = sc[nn] * inv;
    }
}

// ---------------- build x : fp32 (b,66,40) + bf16 padded (b,66,64) ------------
__global__ __launch_bounds__(256) void xbuild(const float* __restrict__ src,
                                              const float* __restrict__ att,
                                              const float* __restrict__ dct20,
                                              float* __restrict__ x,
                                              u16* __restrict__ xbf) {
    const int b = blockIdx.x, tid = threadIdx.x;
    __shared__ float s_src[50 * 66];
    __shared__ float s_sacc[VL * 66];
    __shared__ float s_d[DCTN * VL];
    __shared__ float s_att[16];
    for (int i = tid; i < 3300; i += 256) s_src[i] = src[b * 3300 + i];
    for (int i = tid; i < DCTN * VL; i += 256) s_d[i] = dct20[i];
    if (tid < 16) s_att[tid] = att[b * 16 + tid];
    __syncthreads();
    for (int i = tid; i < VL * 66; i += 256) {
        int v = i / 66, f = i - (i / 66) * 66;
        float a = 0.f;
#pragma unroll
        for (int n = 0; n < 16; ++n) a += s_att[n] * s_src[(n + v) * 66 + f];
        s_sacc[i] = a;
    }
    __syncthreads();
    for (int i = tid; i < 66 * DCTN; i += 256) {
        int f = i / DCTN, kq = i - (i / DCTN) * DCTN;
        float din = 0.f, datt = 0.f;
        for (int v = 0; v < VL; ++v) {
            float dv = s_d[kq * VL + v];
            int t2 = (v < 10) ? (40 + v) : 49;
            din += dv * s_src[t2 * 66 + f];
            datt += dv * s_sacc[v * 66 + f];
        }
        x[b * 2640 + f * 40 + kq] = din;
        x[b * 2640 + f * 40 + 20 + kq] = datt;
        xbf[(size_t)b * 4224 + f * 64 + kq] = f2bf(din);
        xbf[(size_t)b * 4224 + f * 64 + 20 + kq] = f2bf(datt);
    }
    for (int i = tid; i < 66 * 24; i += 256) {
        int f = i / 24, kp = 40 + (i - (i / 24) * 24);
        xbf[(size_t)b * 4224 + f * 64 + kp] = 0;
    }
}

// ---------------- out[b,v,f] = sum_k dct20[k,v]*dctout[b,f,k] ----------------
__global__ __launch_bounds__(256) void final_out(const float* __restrict__ dctout,
                                                 const float* __restrict__ dct20,
                                                 float* __restrict__ out) {
    const int b = blockIdx.x, tid = threadIdx.x;
    __shared__ float ds[DCTN * VL];
    __shared__ float dos[66 * 20];
    for (int i = tid; i < DCTN * VL; i += 256) ds[i] = dct20[i];
    for (int i = tid; i < 1320; i += 256) dos[i] = dctout[(size_t)b * 1320 + i];
    __syncthreads();
    for (int o = tid; o < VL * 66; o += 256) {
        int v = o / 66, f = o - (o / 66) * 66;
        float acc = 0.f;
#pragma unroll
        for (int k = 0; k < DCTN; ++k) acc += ds[k * VL + v] * dos[f * 20 + k];
        out[(size_t)b * 2310 + o] = acc;
    }
}

extern "C" void kernel_launch(void* const* d_in, const int* in_sizes, int n_in,
                              void* d_out, int out_size, void* d_ws, size_t ws_size,
                              hipStream_t stream) {
    const float* src     = (const float*)d_in[0];
    const float* Wq1     = (const float*)d_in[1];
    const float* Wq2     = (const float*)d_in[2];
    const float* Wk1     = (const float*)d_in[3];
    const float* Wk2     = (const float*)d_in[4];
    const float* gc1_W   = (const float*)d_in[5];
    const float* gc1_att = (const float*)d_in[6];
    const float* gc1_b   = (const float*)d_in[7];
    const float* bn1_g   = (const float*)d_in[8];
    const float* bn1_b   = (const float*)d_in[9];
    const float* gcb_W   = (const float*)d_in[10];
    const float* gcb_att = (const float*)d_in[11];
    const float* gcb_b   = (const float*)d_in[12];
    const float* gcb_g   = (const float*)d_in[13];
    const float* gcb_be  = (const float*)d_in[14];
    const float* gc7_W   = (const float*)d_in[15];
    const float* gc7_att = (const float*)d_in[16];
    const float* gc7_b   = (const float*)d_in[17];
    float* out = (float*)d_out;

    unsigned char* base = (unsigned char*)d_ws;
    size_t off = 0;
    auto take = [&](size_t bytes) -> void* {
        void* p = base + off;
        off += (bytes + 255) & ~(size_t)255;
        return p;
    };
    u16*   yA     = (u16*)take((size_t)33792 * 512 * 2);
    u16*   yB     = (u16*)take((size_t)33792 * 512 * 2);
    u16*   ub     = (u16*)take((size_t)33792 * 512 * 2);
    u16*   u1     = (u16*)take((size_t)33792 * 64 * 2);
    float* xb     = (float*)take((size_t)512 * 2640 * 4);
    u16*   xbf    = (u16*)take((size_t)512 * 4224 * 2);
    float* dct20  = (float*)take(2800);
    float* dctout = (float*)take((size_t)512 * 1320 * 4);
    u16*   key1   = (u16*)take((size_t)512 * 20 * 512 * 2);
    u16*   q1     = (u16*)take((size_t)512 * 5 * 512 * 2);
    float* keyT   = (float*)take((size_t)8192 * 512 * 4);
    float* queryT = (float*)take((size_t)512 * 512 * 4);
    float* attw   = (float*)take((size_t)512 * 16 * 4);
    u16*   WtGcb  = (u16*)take((size_t)4 * 512 * 512 * 2);
    u16*   WtGc1  = (u16*)take((size_t)512 * 64 * 2);
    u16*   WtGc7  = (u16*)take((size_t)128 * 512 * 2);
    u16*   WtW1k  = (u16*)take((size_t)512 * 416 * 2);
    u16*   WtW1q  = (u16*)take((size_t)512 * 416 * 2);
    u16*   WtW2k  = (u16*)take((size_t)512 * 2560 * 2);
    u16*   WtW2q  = (u16*)take((size_t)512 * 2560 * 2);
    u16*   Abf    = (u16*)take((size_t)6 * 8320 * 2);

    dct_kernel<<<2, 384, 0, stream>>>(dct20);
    cvt_att<<<dim3(33, 6), 256, 0, stream>>>(gc1_att, gcb_att, gc7_att, Abf);
    cvt_gcb<<<dim3(1024, 4), 256, 0, stream>>>(gcb_W, WtGcb);
    cvt_gc1<<<128, 256, 0, stream>>>(gc1_W, WtGc1);
    cvt_gc7<<<256, 256, 0, stream>>>(gc7_W, WtGc7);
    cvt_w1<<<832, 256, 0, stream>>>(Wk1, WtW1k);
    cvt_w1<<<832, 256, 0, stream>>>(Wq1, WtW1q);
    cvt_w2<<<5120, 256, 0, stream>>>(Wk2, WtW2k);
    cvt_w2<<<5120, 256, 0, stream>>>(Wq2, WtW2q);

    // conv stacks (im2col is a strided view -> read inputs directly)
    gemm_uni<2, 0, 20, 25, 0><<<dim3(80, 4), 256, 0, stream>>>(
        src, WtW1k, key1, 10240, 416, 512, 512, nullptr, nullptr, nullptr, nullptr, nullptr);
    gemm_uni<2, 0, 5, 10, 40><<<dim3(20, 4), 256, 0, stream>>>(
        src, WtW1q, q1, 2560, 416, 512, 512, nullptr, nullptr, nullptr, nullptr, nullptr);
    gemm_uni<1, 1, 16, 20, 0><<<dim3(64, 4), 256, 0, stream>>>(
        key1, WtW2k, keyT, 8192, 2560, 512, 512, nullptr, nullptr, nullptr, nullptr, nullptr);
    gemm_uni<1, 1, 1, 5, 0><<<dim3(4, 4), 256, 0, stream>>>(
        q1, WtW2q, queryT, 512, 2560, 512, 512, nullptr, nullptr, nullptr, nullptr, nullptr);
    att_kernel<<<BSZ, 256, 0, stream>>>(queryT, keyT, attw);
    xbuild<<<BSZ, 256, 0, stream>>>(src, attw, dct20, xb, xbf);

    // gc1: u1 = A1 @ x ; yA = tanh(bn(u1 @ W1 + b))
    amul<64, 64><<<dim3(512, 1), 256, 0, stream>>>(xbf, Abf, u1);
    gemm_uni<0, 2, 1, 1, 0><<<dim3(264, 4), 256, 0, stream>>>(
        u1, WtGc1, yA, 33792, 64, 512, 512, gc1_b, bn1_g, bn1_b, nullptr, nullptr);

    // stages
    for (int st = 0; st < 2; ++st) {
        const u16* W0 = WtGcb + (size_t)(st * 2 + 0) * 262144;
        const u16* W1 = WtGcb + (size_t)(st * 2 + 1) * 262144;
        const u16* A0 = Abf + (size_t)(1 + st * 2) * 8320;
        const u16* A1 = Abf + (size_t)(2 + st * 2) * 8320;
        const float* b0  = gcb_b + (size_t)(st * 2 + 0) * 512;
        const float* b1  = gcb_b + (size_t)(st * 2 + 1) * 512;
        const float* g0  = gcb_g + (size_t)(st * 2 + 0) * 33792;
        const float* g1  = gcb_g + (size_t)(st * 2 + 1) * 33792;
        const float* be0 = gcb_be + (size_t)(st * 2 + 0) * 33792;
        const float* be1 = gcb_be + (size_t)(st * 2 + 1) * 33792;
        amul<128, 512><<<dim3(512, 4), 256, 0, stream>>>(yA, A0, ub);
        gemm_uni<0, 2, 1, 1, 0><<<dim3(264, 4), 256, 0, stream>>>(
            ub, W0, yB, 33792, 512, 512, 512, b0, g0, be0, nullptr, nullptr);
        amul<128, 512><<<dim3(512, 4), 256, 0, stream>>>(yB, A1, ub);
        gemm_uni<0, 3, 1, 1, 0><<<dim3(264, 4), 256, 0, stream>>>(
            ub, W1, yA, 33792, 512, 512, 512, b1, g1, be1, yA, nullptr);
    }

    // gc7: dctout = (A7 @ y) @ W7 + b7 + x  (first 20 cols)
    amul<128, 512><<<dim3(512, 4), 256, 0, stream>>>(yA, Abf + (size_t)5 * 8320, ub);
    gemm_uni<0, 4, 1, 1, 0><<<dim3(264, 1), 256, 0, stream>>>(
        ub, WtGc7, dctout, 33792, 512, 20, 20, gc7_b, nullptr, nullptr, nullptr, xb);
    final_out<<<BSZ, 256, 0, stream>>>(dctout, dct20, out);
}

// Round 5
// 808.442 us; speedup vs baseline: 3.2921x; 1.0441x over previous
//
#include <hip/hip_runtime.h>
#include <math.h>

#define PI_D 3.14159265358979323846

#define BSZ   512
#define NODE  66
#define VL    35
#define DCTN  20

static constexpr float BN_INVS = 0.99999500003749969f; // 1/sqrt(1+1e-5)

typedef unsigned short u16;
using bf16x8 = __attribute__((ext_vector_type(8))) short;
using f32x4  = __attribute__((ext_vector_type(4))) float;

__device__ inline u16 f2bf(float f) {
    union { float f; unsigned int u; } v; v.f = f;
    unsigned int r = v.u + 0x7FFFu + ((v.u >> 16) & 1u);
    return (u16)(r >> 16);
}
__device__ inline float bf2f(u16 b) {
    union { unsigned int u; float f; } v; v.u = ((unsigned int)b) << 16;
    return v.f;
}

// ---------------- dct20 (20 x 35), orthonormal DCT-II rows ----------------
__global__ void dct_kernel(float* __restrict__ dct20) {
    int i = blockIdx.x * blockDim.x + threadIdx.x;
    if (i < DCTN * VL) {
        int k = i / VL, v = i - k * VL;
        double w = (k == 0) ? sqrt(1.0 / VL) : sqrt(2.0 / VL);
        dct20[i] = (float)(w * cos(PI_D * (v + 0.5) * k / (double)VL));
    }
}

// ---------------- weight conversion / transpose to bf16 ----------------
__global__ void cvt_gcb(const float* __restrict__ W, u16* __restrict__ Wt) {
    int l = blockIdx.y;
    int i = blockIdx.x * 256 + threadIdx.x;
    int n = i >> 9, k = i & 511;
    Wt[(size_t)l * 262144 + i] = f2bf(W[(size_t)l * 262144 + (size_t)k * 512 + n]);
}
__global__ void cvt_gc1(const float* __restrict__ W, u16* __restrict__ Wt) {
    int i = blockIdx.x * 256 + threadIdx.x;
    int n = i >> 6, k = i & 63;
    Wt[i] = (k < 40) ? f2bf(W[k * 512 + n]) : (u16)0;
}
__global__ void cvt_gc7(const float* __restrict__ W, u16* __restrict__ Wt) {
    int i = blockIdx.x * 256 + threadIdx.x;
    int n = i >> 9, k = i & 511;
    Wt[i] = (n < 20) ? f2bf(W[k * 40 + n]) : (u16)0;
}
__global__ void cvt_w1(const float* __restrict__ W, u16* __restrict__ Wt) {
    int i = blockIdx.x * 256 + threadIdx.x;
    int d = i / 416, k = i - d * 416;
    float v = 0.f;
    if (k < 396) { int h = k / 66, c = k - h * 66; v = W[d * 396 + c * 6 + h]; }
    Wt[i] = f2bf(v);
}
__global__ void cvt_w2(const float* __restrict__ W, u16* __restrict__ Wt) {
    int i = blockIdx.x * 256 + threadIdx.x;
    int d = i / 2560, k = i - d * 2560;
    int h = k >> 9, c = k & 511;
    Wt[i] = f2bf(W[(size_t)d * 2560 + c * 5 + h]);
}
// A matrices (66x66) -> prepadded bf16 [6][80][104]
__global__ void cvt_att(const float* __restrict__ gc1A, const float* __restrict__ gcbA,
                        const float* __restrict__ gc7A, u16* __restrict__ Abf) {
    int l = blockIdx.y;
    int i = blockIdx.x * 256 + threadIdx.x;
    if (i < 8320) {
        int r = i / 104, c = i - (i / 104) * 104;
        float v = 0.f;
        if (r < 66 && c < 66) {
            const float* A = (l == 0) ? gc1A : (l <= 4 ? gcbA + (size_t)(l - 1) * 4356 : gc7A);
            v = A[r * 66 + c];
        }
        Abf[(size_t)l * 8320 + i] = f2bf(v);
    }
}

// ---------------- fused GCN layer: y' = epi( A_g @ (Y @ W) ) ----------------
// Block = 2 whole batches (132 rows, staged as 144) x 128 f-cols. Phase 1:
// t = Y@W via MFMA into acc; pack t^T into zT LDS (batch0 at col 0, batch1 at
// col 72 for 16B alignment; gaps zeroed so A's zero-pad kills garbage).
// Phase 2: A(80x96pad) @ zT via MFMA; epilogue bias+bn+tanh(+res) or gc7.
// EPI: 2 = bn+tanh -> bf16 y ; 3 = bn+tanh+res -> bf16 y ; 4 = +bias+x -> fp32 dctout
template<int EPI>
__global__ __launch_bounds__(256) void gc_fused(const u16* __restrict__ Y,
                                                const u16* __restrict__ Wt,
                                                const u16* __restrict__ Ab,
                                                void* __restrict__ Yout, int K,
                                                const float* __restrict__ bias,
                                                const float* __restrict__ g,
                                                const float* __restrict__ be,
                                                const u16* __restrict__ yres,
                                                const float* __restrict__ xres) {
    __shared__ u16 As[144][40];
    __shared__ u16 Bs[128][40];
    __shared__ u16 zT[128][168];
    const int tid = threadIdx.x;
    const int b0 = blockIdx.x * 2;
    const int n0 = blockIdx.y * 128;
    const int lane = tid & 63, w = tid >> 6;
    const int row16 = lane & 15, grp = lane >> 4;

    // zero zT pad columns [66,72) and [138,168)
    for (int i = tid; i < 128 * 36; i += 256) {
        int f = i / 36, j = i - (i / 36) * 36;
        int c = (j < 6) ? (66 + j) : (132 + j); // j>=6 -> 138..167
        zT[f][c] = 0;
    }

    const int sr = tid >> 1, sq = (tid & 1) * 16;
    long r1 = (long)b0 * 66 + sr;        if (r1 > 33791) r1 = 33791;
    long r2 = (long)b0 * 66 + 128 + sr;  if (r2 > 33791) r2 = 33791; // tid<32 only
    const u16* ap1 = Y + (size_t)r1 * K + sq;
    const u16* ap2 = Y + (size_t)r2 * K + sq;
    const u16* bp  = Wt + (size_t)(n0 + sr) * K + sq;

    f32x4 acc[9][2] = {};
    for (int k0 = 0; k0 < K; k0 += 32) {
        *(bf16x8*)&As[sr][sq]     = *(const bf16x8*)(ap1 + k0);
        *(bf16x8*)&As[sr][sq + 8] = *(const bf16x8*)(ap1 + k0 + 8);
        if (tid < 32) {
            *(bf16x8*)&As[128 + sr][sq]     = *(const bf16x8*)(ap2 + k0);
            *(bf16x8*)&As[128 + sr][sq + 8] = *(const bf16x8*)(ap2 + k0 + 8);
        }
        *(bf16x8*)&Bs[sr][sq]     = *(const bf16x8*)(bp + k0);
        *(bf16x8*)&Bs[sr][sq + 8] = *(const bf16x8*)(bp + k0 + 8);
        __syncthreads();
        bf16x8 a[9], b[2];
#pragma unroll
        for (int mt = 0; mt < 9; ++mt) a[mt] = *(const bf16x8*)&As[mt * 16 + row16][grp * 8];
#pragma unroll
        for (int nt = 0; nt < 2; ++nt) b[nt] = *(const bf16x8*)&Bs[w * 32 + nt * 16 + row16][grp * 8];
#pragma unroll
        for (int mt = 0; mt < 9; ++mt)
#pragma unroll
            for (int nt = 0; nt < 2; ++nt)
                acc[mt][nt] = __builtin_amdgcn_mfma_f32_16x16x32_bf16(a[mt], b[nt], acc[mt][nt], 0, 0, 0);
        __syncthreads();
    }

    // pack t^T into zT (batch1 shifted by +6 cols -> base 72)
#pragma unroll
    for (int mt = 0; mt < 9; ++mt) {
        int m = mt * 16 + grp * 4;
        if (m < 132) {
#pragma unroll
            for (int nt = 0; nt < 2; ++nt) {
                int f = w * 32 + nt * 16 + row16;
                u16 e0 = f2bf(acc[mt][nt][0]), e1 = f2bf(acc[mt][nt][1]);
                u16 e2 = f2bf(acc[mt][nt][2]), e3 = f2bf(acc[mt][nt][3]);
                if (m + 3 < 66 || m >= 66) {
                    int col = (m < 66) ? m : m + 6;
                    *(unsigned int*)&zT[f][col]     = (unsigned int)e0 | ((unsigned int)e1 << 16);
                    *(unsigned int*)&zT[f][col + 2] = (unsigned int)e2 | ((unsigned int)e3 << 16);
                } else { // straddles batch boundary (m=64): 64,65 | 72,73
                    zT[f][64] = e0; zT[f][65] = e1; zT[f][72] = e2; zT[f][73] = e3;
                }
            }
        }
    }

    // A fragments straight from global (L2-hot, same for all waves)
    bf16x8 aA[5][3];
#pragma unroll
    for (int mt = 0; mt < 5; ++mt)
#pragma unroll
        for (int k2 = 0; k2 < 3; ++k2)
            aA[mt][k2] = *(const bf16x8*)&Ab[(mt * 16 + row16) * 104 + k2 * 32 + grp * 8];
    __syncthreads();

    f32x4 acc2[2][5][2] = {};
#pragma unroll
    for (int bb = 0; bb < 2; ++bb) {
        const int base = bb * 72;
#pragma unroll
        for (int k2 = 0; k2 < 3; ++k2) {
            bf16x8 bz[2];
#pragma unroll
            for (int ft = 0; ft < 2; ++ft)
                bz[ft] = *(const bf16x8*)&zT[w * 32 + ft * 16 + row16][base + k2 * 32 + grp * 8];
#pragma unroll
            for (int mt = 0; mt < 5; ++mt)
#pragma unroll
                for (int ft = 0; ft < 2; ++ft)
                    acc2[bb][mt][ft] = __builtin_amdgcn_mfma_f32_16x16x32_bf16(aA[mt][k2], bz[ft], acc2[bb][mt][ft], 0, 0, 0);
        }
    }

    // epilogue
#pragma unroll
    for (int bb = 0; bb < 2; ++bb) {
        const int bidx = b0 + bb;
#pragma unroll
        for (int mt = 0; mt < 5; ++mt) {
            int nb = mt * 16 + grp * 4;
#pragma unroll
            for (int ft = 0; ft < 2; ++ft) {
                int c = n0 + w * 32 + ft * 16 + row16;
#pragma unroll
                for (int j = 0; j < 4; ++j) {
                    int n = nb + j;
                    if (n < 66) {
                        float v = acc2[bb][mt][ft][j];
                        if constexpr (EPI == 4) {
                            if (c < 20)
                                ((float*)Yout)[(size_t)bidx * 1320 + n * 20 + c] =
                                    v + bias[c] + xres[(size_t)bidx * 2640 + n * 40 + c];
                        } else {
                            int gi = n * 512 + c;
                            float z = v + bias[c];
                            float t = tanhf(z * (g[gi] * BN_INVS) + be[gi]);
                            if constexpr (EPI == 3) t += bf2f(yres[((size_t)bidx * 66 + n) * 512 + c]);
                            ((u16*)Yout)[((size_t)bidx * 66 + n) * 512 + c] = f2bf(t);
                        }
                    }
                }
            }
        }
    }
}

// ---------------- unified bf16 MFMA GEMM (conv stacks) ----------------
// ASRC: 1 = bf16 conv window (in[b][TIN][512], k-contig);
//       2 = fp32 src window (src[b][50][66], base (T0+t)*66, k<396 guard, *1e-3)
// EPI:  0 = relu -> bf16 (ldc); 1 = relu -> fp32 (ldc)
template<int ASRC, int EPI, int TOUT, int TIN, int T0>
__global__ __launch_bounds__(256) void gemm_uni(const void* __restrict__ Asrc,
                                                const u16* __restrict__ Bt,
                                                void* __restrict__ Cout,
                                                int M, int K, int Nvalid, int ldc) {
    __shared__ u16 As[128][40];
    __shared__ u16 Bs[128][40];
    const int tid = threadIdx.x;
    const int r0 = blockIdx.x * 128, n0 = blockIdx.y * 128;
    const int lane = tid & 63, w = tid >> 6;
    const int wr = (w >> 1) * 64, wc = (w & 1) * 64;
    const int row16 = lane & 15, grp = lane >> 4;
    const int sr = tid >> 1, sq = (tid & 1) * 16;

    const u16* ap = nullptr;
    const float* apf = nullptr;
    if constexpr (ASRC == 1) {
        int R = r0 + sr; int b = R / TOUT, t = R - b * TOUT;
        ap = (const u16*)Asrc + ((size_t)b * TIN + t) * 512 + sq;
    } else {
        int R = r0 + sr; int b = R / TOUT, t = R - b * TOUT;
        apf = (const float*)Asrc + (size_t)b * 3300 + (T0 + t) * 66 + sq;
    }
    const u16* bp = Bt + (size_t)(n0 + sr) * K + sq;

    f32x4 acc[4][4] = {};
    for (int k0 = 0; k0 < K; k0 += 32) {
        if constexpr (ASRC == 1) {
            *(bf16x8*)&As[sr][sq]     = *(const bf16x8*)(ap + k0);
            *(bf16x8*)&As[sr][sq + 8] = *(const bf16x8*)(ap + k0 + 8);
        } else {
#pragma unroll
            for (int j = 0; j < 16; ++j) {
                int k = k0 + sq + j;
                float vin = 0.f;
                if (k < 396) vin = apf[k0 + j];
                As[sr][sq + j] = f2bf(vin * 1e-3f);
            }
        }
        *(bf16x8*)&Bs[sr][sq]     = *(const bf16x8*)(bp + k0);
        *(bf16x8*)&Bs[sr][sq + 8] = *(const bf16x8*)(bp + k0 + 8);
        __syncthreads();
        bf16x8 a[4], b[4];
#pragma unroll
        for (int m = 0; m < 4; ++m) a[m] = *(const bf16x8*)&As[wr + m * 16 + row16][grp * 8];
#pragma unroll
        for (int n = 0; n < 4; ++n) b[n] = *(const bf16x8*)&Bs[wc + n * 16 + row16][grp * 8];
#pragma unroll
        for (int m = 0; m < 4; ++m)
#pragma unroll
            for (int n = 0; n < 4; ++n)
                acc[m][n] = __builtin_amdgcn_mfma_f32_16x16x32_bf16(a[m], b[n], acc[m][n], 0, 0, 0);
        __syncthreads();
    }
#pragma unroll
    for (int m = 0; m < 4; ++m) {
        int rb = r0 + wr + m * 16 + grp * 4;
#pragma unroll
        for (int n = 0; n < 4; ++n) {
            int c = n0 + wc + n * 16 + row16;
            if (c < Nvalid) {
#pragma unroll
                for (int j = 0; j < 4; ++j) {
                    float v = fmaxf(acc[m][n][j], 0.f);
                    if constexpr (EPI == 0) ((u16*)Cout)[(size_t)(rb + j) * ldc + c] = f2bf(v);
                    else                    ((float*)Cout)[(size_t)(rb + j) * ldc + c] = v;
                }
            }
        }
    }
}

// ---------------- attention weights: att[b,n] ----------------
__global__ __launch_bounds__(256) void att_kernel(const float* __restrict__ qT,
                                                  const float* __restrict__ kT,
                                                  float* __restrict__ att) {
    const int b = blockIdx.x, tid = threadIdx.x;
    __shared__ float part[256];
    __shared__ float sc[16];
    int n = tid >> 4, j = tid & 15;
    const float* q = qT + b * 512;
    const float* k = kT + b * 8192 + n * 512;
    float acc = 0.f;
    for (int d = j; d < 512; d += 16) acc += q[d] * k[d];
    part[tid] = acc;
    __syncthreads();
    if (tid < 16) {
        float s = 0.f;
        for (int jj = 0; jj < 16; ++jj) s += part[tid * 16 + jj];
        sc[tid] = s + 1e-15f;
    }
    __syncthreads();
    if (tid == 0) {
        float tot = 0.f;
        for (int nn = 0; nn < 16; ++nn) tot += sc[nn];
        float inv = 1.f / tot;
        for (int nn = 0; nn < 16; ++nn) att[b * 16 + nn] = sc[nn] * inv;
    }
}

// ---------------- build x : fp32 (b,66,40) + bf16 padded (b,66,64) ------------
__global__ __launch_bounds__(256) void xbuild(const float* __restrict__ src,
                                              const float* __restrict__ att,
                                              const float* __restrict__ dct20,
                                              float* __restrict__ x,
                                              u16* __restrict__ xbf) {
    const int b = blockIdx.x, tid = threadIdx.x;
    __shared__ float s_src[50 * 66];
    __shared__ float s_sacc[VL * 66];
    __shared__ float s_d[DCTN * VL];
    __shared__ float s_att[16];
    for (int i = tid; i < 3300; i += 256) s_src[i] = src[b * 3300 + i];
    for (int i = tid; i < DCTN * VL; i += 256) s_d[i] = dct20[i];
    if (tid < 16) s_att[tid] = att[b * 16 + tid];
    __syncthreads();
    for (int i = tid; i < VL * 66; i += 256) {
        int v = i / 66, f = i - (i / 66) * 66;
        float a = 0.f;
#pragma unroll
        for (int n = 0; n < 16; ++n) a += s_att[n] * s_src[(n + v) * 66 + f];
        s_sacc[i] = a;
    }
    __syncthreads();
    for (int i = tid; i < 66 * DCTN; i += 256) {
        int f = i / DCTN, kq = i - (i / DCTN) * DCTN;
        float din = 0.f, datt = 0.f;
        for (int v = 0; v < VL; ++v) {
            float dv = s_d[kq * VL + v];
            int t2 = (v < 10) ? (40 + v) : 49;
            din += dv * s_src[t2 * 66 + f];
            datt += dv * s_sacc[v * 66 + f];
        }
        x[b * 2640 + f * 40 + kq] = din;
        x[b * 2640 + f * 40 + 20 + kq] = datt;
        xbf[(size_t)b * 4224 + f * 64 + kq] = f2bf(din);
        xbf[(size_t)b * 4224 + f * 64 + 20 + kq] = f2bf(datt);
    }
    for (int i = tid; i < 66 * 24; i += 256) {
        int f = i / 24, kp = 40 + (i - (i / 24) * 24);
        xbf[(size_t)b * 4224 + f * 64 + kp] = 0;
    }
}

// ---------------- out[b,v,f] = sum_k dct20[k,v]*dctout[b,f,k] ----------------
__global__ __launch_bounds__(256) void final_out(const float* __restrict__ dctout,
                                                 const float* __restrict__ dct20,
                                                 float* __restrict__ out) {
    const int b = blockIdx.x, tid = threadIdx.x;
    __shared__ float ds[DCTN * VL];
    __shared__ float dos[66 * 20];
    for (int i = tid; i < DCTN * VL; i += 256) ds[i] = dct20[i];
    for (int i = tid; i < 1320; i += 256) dos[i] = dctout[(size_t)b * 1320 + i];
    __syncthreads();
    for (int o = tid; o < VL * 66; o += 256) {
        int v = o / 66, f = o - (o / 66) * 66;
        float acc = 0.f;
#pragma unroll
        for (int k = 0; k < DCTN; ++k) acc += ds[k * VL + v] * dos[f * 20 + k];
        out[(size_t)b * 2310 + o] = acc;
    }
}

extern "C" void kernel_launch(void* const* d_in, const int* in_sizes, int n_in,
                              void* d_out, int out_size, void* d_ws, size_t ws_size,
                              hipStream_t stream) {
    const float* src     = (const float*)d_in[0];
    const float* Wq1     = (const float*)d_in[1];
    const float* Wq2     = (const float*)d_in[2];
    const float* Wk1     = (const float*)d_in[3];
    const float* Wk2     = (const float*)d_in[4];
    const float* gc1_W   = (const float*)d_in[5];
    const float* gc1_att = (const float*)d_in[6];
    const float* gc1_b   = (const float*)d_in[7];
    const float* bn1_g   = (const float*)d_in[8];
    const float* bn1_b   = (const float*)d_in[9];
    const float* gcb_W   = (const float*)d_in[10];
    const float* gcb_att = (const float*)d_in[11];
    const float* gcb_b   = (const float*)d_in[12];
    const float* gcb_g   = (const float*)d_in[13];
    const float* gcb_be  = (const float*)d_in[14];
    const float* gc7_W   = (const float*)d_in[15];
    const float* gc7_att = (const float*)d_in[16];
    const float* gc7_b   = (const float*)d_in[17];
    float* out = (float*)d_out;

    unsigned char* base = (unsigned char*)d_ws;
    size_t off = 0;
    auto take = [&](size_t bytes) -> void* {
        void* p = base + off;
        off += (bytes + 255) & ~(size_t)255;
        return p;
    };
    u16*   yA     = (u16*)take((size_t)33792 * 512 * 2);
    u16*   yB     = (u16*)take((size_t)33792 * 512 * 2);
    float* xb     = (float*)take((size_t)512 * 2640 * 4);
    u16*   xbf    = (u16*)take((size_t)512 * 4224 * 2);
    float* dct20  = (float*)take(2800);
    float* dctout = (float*)take((size_t)512 * 1320 * 4);
    u16*   key1   = (u16*)take((size_t)512 * 20 * 512 * 2);
    u16*   q1     = (u16*)take((size_t)512 * 5 * 512 * 2);
    float* keyT   = (float*)take((size_t)8192 * 512 * 4);
    float* queryT = (float*)take((size_t)512 * 512 * 4);
    float* attw   = (float*)take((size_t)512 * 16 * 4);
    u16*   WtGcb  = (u16*)take((size_t)4 * 512 * 512 * 2);
    u16*   WtGc1  = (u16*)take((size_t)512 * 64 * 2);
    u16*   WtGc7  = (u16*)take((size_t)128 * 512 * 2);
    u16*   WtW1k  = (u16*)take((size_t)512 * 416 * 2);
    u16*   WtW1q  = (u16*)take((size_t)512 * 416 * 2);
    u16*   WtW2k  = (u16*)take((size_t)512 * 2560 * 2);
    u16*   WtW2q  = (u16*)take((size_t)512 * 2560 * 2);
    u16*   Abf    = (u16*)take((size_t)6 * 8320 * 2);

    dct_kernel<<<2, 384, 0, stream>>>(dct20);
    cvt_att<<<dim3(33, 6), 256, 0, stream>>>(gc1_att, gcb_att, gc7_att, Abf);
    cvt_gcb<<<dim3(1024, 4), 256, 0, stream>>>(gcb_W, WtGcb);
    cvt_gc1<<<128, 256, 0, stream>>>(gc1_W, WtGc1);
    cvt_gc7<<<256, 256, 0, stream>>>(gc7_W, WtGc7);
    cvt_w1<<<832, 256, 0, stream>>>(Wk1, WtW1k);
    cvt_w1<<<832, 256, 0, stream>>>(Wq1, WtW1q);
    cvt_w2<<<5120, 256, 0, stream>>>(Wk2, WtW2k);
    cvt_w2<<<5120, 256, 0, stream>>>(Wq2, WtW2q);

    // conv stacks (im2col is a strided view -> read inputs directly)
    gemm_uni<2, 0, 20, 25, 0><<<dim3(80, 4), 256, 0, stream>>>(
        src, WtW1k, key1, 10240, 416, 512, 512);
    gemm_uni<2, 0, 5, 10, 40><<<dim3(20, 4), 256, 0, stream>>>(
        src, WtW1q, q1, 2560, 416, 512, 512);
    gemm_uni<1, 1, 16, 20, 0><<<dim3(64, 4), 256, 0, stream>>>(
        key1, WtW2k, keyT, 8192, 2560, 512, 512);
    gemm_uni<1, 1, 1, 5, 0><<<dim3(4, 4), 256, 0, stream>>>(
        q1, WtW2q, queryT, 512, 2560, 512, 512);
    att_kernel<<<BSZ, 256, 0, stream>>>(queryT, keyT, attw);
    xbuild<<<BSZ, 256, 0, stream>>>(src, attw, dct20, xb, xbf);

    // gc1: yA = tanh(bn(A1 @ (x @ W1) + b))
    gc_fused<2><<<dim3(256, 4), 256, 0, stream>>>(
        xbf, WtGc1, Abf, yA, 64, gc1_b, bn1_g, bn1_b, nullptr, nullptr);

    // stages
    for (int st = 0; st < 2; ++st) {
        const u16* W0 = WtGcb + (size_t)(st * 2 + 0) * 262144;
        const u16* W1 = WtGcb + (size_t)(st * 2 + 1) * 262144;
        const u16* A0 = Abf + (size_t)(1 + st * 2) * 8320;
        const u16* A1 = Abf + (size_t)(2 + st * 2) * 8320;
        const float* b0  = gcb_b + (size_t)(st * 2 + 0) * 512;
        const float* b1  = gcb_b + (size_t)(st * 2 + 1) * 512;
        const float* g0  = gcb_g + (size_t)(st * 2 + 0) * 33792;
        const float* g1  = gcb_g + (size_t)(st * 2 + 1) * 33792;
        const float* be0 = gcb_be + (size_t)(st * 2 + 0) * 33792;
        const float* be1 = gcb_be + (size_t)(st * 2 + 1) * 33792;
        gc_fused<2><<<dim3(256, 4), 256, 0, stream>>>(
            yA, W0, A0, yB, 512, b0, g0, be0, nullptr, nullptr);
        gc_fused<3><<<dim3(256, 4), 256, 0, stream>>>(
            yB, W1, A1, yA, 512, b1, g1, be1, yA, nullptr);
    }

    // gc7: dctout = A7 @ (y @ W7) + b7 + x  (first 20 cols)
    gc_fused<4><<<dim3(256, 1), 256, 0, stream>>>(
        yA, WtGc7, Abf + (size_t)5 * 8320, dctout, 512, gc7_b, nullptr, nullptr, nullptr, xb);
    final_out<<<BSZ, 256, 0, stream>>>(dctout, dct20, out);
}